// Round 1
// 162.179 us; speedup vs baseline: 1.0315x; 1.0315x over previous
//
#include <hip/hip_runtime.h>

#define N_TOK 131072
#define TILE 64              // tokens per block (was 32): halves per-token L2 weight traffic
#define NT_MAX 2064          // N_TOK/TILE + 16 tasks worth of padding tiles

typedef __attribute__((ext_vector_type(8))) short s8v;
typedef __attribute__((ext_vector_type(4))) float f4v;
typedef unsigned short ushort_t;

__device__ __forceinline__ unsigned short f2bf(float x) {
    union { float f; unsigned u; } v; v.f = x;
    unsigned r = v.u + 0x7fffu + ((v.u >> 16) & 1u);   // RNE (prep only)
    return (unsigned short)(r >> 16);
}

// round-half-up pack of two f32 -> packed bf16x2 via v_perm_b32 (3 VALU ops)
__device__ __forceinline__ unsigned pk2(float a, float b) {
    union { float f; unsigned u; } x, y; x.f = a; y.f = b;
    return __byte_perm(x.u + 0x8000u, y.u + 0x8000u, 0x7632);
}

// tanh via fast exp + fast rcp: mul, exp, add, rcp, fma (no precise-div sequence)
__device__ __forceinline__ float tanh_fast(float x) {
    float e = __expf(2.0f * x);
    float r = __builtin_amdgcn_rcpf(e + 1.0f);
    return __builtin_fmaf(-2.0f, r, 1.0f);
}

// ------------------------------------------------- fused prep + hist
// blocks [0,224): repack weights to bf16 MFMA fragments (one 16B write/thread).
// Fragment r = (ftile*(K>>5)+kt)*64 + lane; elem j holds W[k][n] with
// n = ftile*16 + (lane&15), k = kt*32 + (lane>>4)*8 + j.  (A operand of
// Y^T = W^T X^T.)   blocks [224,288): 16-bin histogram of task[].
__global__ void prep_hist_kernel(const float* __restrict__ W0, const float* __restrict__ W1,
                                 const float* __restrict__ W2,
                                 ushort_t* __restrict__ W0p, ushort_t* __restrict__ W1p,
                                 ushort_t* __restrict__ W2p,
                                 const int* __restrict__ task, int* __restrict__ blockCounts) {
    if (blockIdx.x < 224) {
        int f = blockIdx.x * 256 + threadIdx.x;   // 57344 total fragments
        const float* src; ushort_t* dst; int K, N;
        if (f < 16384)      { src = W0; dst = W0p; K = 128; N = 256; }
        else if (f < 49152) { src = W1; dst = W1p; K = 256; N = 256; f -= 16384; }
        else                { src = W2; dst = W2p; K = 256; N = 64;  f -= 49152; }
        int fpc = (N >> 4) * (K >> 5) * 64;       // fragments per copy
        int c = f / fpc, r = f % fpc;
        int lane = r & 63;
        int kt = (r >> 6) % (K >> 5);
        int ftile = (r >> 6) / (K >> 5);
        int n = ftile * 16 + (lane & 15);
        int kbase = kt * 32 + (lane >> 4) * 8;
        const float* s = src + (size_t)c * K * N + (size_t)kbase * N + n;
        s8v pk;
#pragma unroll
        for (int j = 0; j < 8; j++) pk[j] = (short)f2bf(s[(size_t)j * N]);
        *reinterpret_cast<s8v*>(dst + ((size_t)(c * fpc + r) << 3)) = pk;
    } else {
        __shared__ int cnt[16];
        int t = threadIdx.x;
        int hb = blockIdx.x - 224;
        if (t < 16) cnt[t] = 0;
        __syncthreads();
        int base = hb * 2048 + t;
#pragma unroll
        for (int i = 0; i < 8; i++) atomicAdd(&cnt[task[base + i * 256]], 1);
        __syncthreads();
        if (t < 16) blockCounts[hb * 16 + t] = cnt[t];
    }
}

// ------------------------------------------------- fused scan + scatter
__global__ void sort_kernel(const int* __restrict__ task, const int* __restrict__ blockCounts,
                            int* __restrict__ tileTask, int* __restrict__ nT,
                            int* __restrict__ perm) {
    __shared__ int cntLds[1024];
    __shared__ int total[16], pref[16], rank[16];
    __shared__ int tokBase[16], tbase[17];
    int t = threadIdx.x, b = blockIdx.x;
    for (int i = t; i < 1024; i += 256) cntLds[i] = blockCounts[i];
    if (t < 16) rank[t] = 0;
    __syncthreads();
    if (t < 16) {
        int tot = 0, pf = 0;
#pragma unroll
        for (int bb = 0; bb < 64; bb++) {
            int v = cntLds[bb * 16 + t];
            tot += v;
            if (bb < b) pf += v;
        }
        total[t] = tot; pref[t] = pf;
    }
    __syncthreads();
    if (t == 0) {
        int tok = 0, tile = 0;
        for (int k = 0; k < 16; k++) {
            tokBase[k] = tok;
            tbase[k] = tile;
            int ntk = (total[k] + TILE - 1) / TILE;
            tok += ntk * TILE;
            tile += ntk;
        }
        tbase[16] = tile;
        if (b == 0) nT[0] = tile;
    }
    __syncthreads();
    if (b == 0) {
        for (int i = t; i < NT_MAX; i += 256) {
            int tk = 0;
            if (i < tbase[16]) {
#pragma unroll
                for (int k = 0; k < 16; k++) if (i >= tbase[k]) tk = k;
            }
            tileTask[i] = tk;
        }
        // fill padding slots with -1 (don't rely on ws poison being >= N_TOK)
        for (int i = t; i < 16 * TILE; i += 256) {
            int k = i >> 6, off = i & (TILE - 1);
            int idx = total[k] + off;
            int lim = ((total[k] + TILE - 1) / TILE) * TILE;
            if (idx < lim) perm[tokBase[k] + idx] = -1;
        }
    }
    int tk[8], my[8];
#pragma unroll
    for (int i = 0; i < 8; i++) {
        int idx = b * 2048 + i * 256 + t;
        tk[i] = task[idx];
        my[i] = atomicAdd(&rank[tk[i]], 1);
    }
#pragma unroll
    for (int i = 0; i < 8; i++) {
        int idx = b * 2048 + i * 256 + t;
        perm[tokBase[tk[i]] + pref[tk[i]] + my[i]] = idx;
    }
}

// ------------------------------------------------- fused MLP, fragment-major LDS
// 64 tokens/block (4 token tiles), 8 waves. Activations stored in exact MFMA-B
// fragment order: frag(tt,kt): elem addr = ((tt*(K/32)+kt)*64 + lane)*8 + j,
// lane = (tok&15) + 16*((k&31)>>3), j = k&7. Reads are contiguous 1KB/wave
// ds_read_b128. Weight fragments loaded once per (mi,kt), reused across 4 nt
// -> per-block L2 weight stream (256KB) amortized over 2x the tokens.
// LDS = 32KB (H1) + 32KB (X/H2 overlay) = 64KB -> 2 blocks/CU, 16 waves/CU.
__launch_bounds__(512, 4)
__global__ void mlp_kernel(const float* __restrict__ x_in,
                           const int* __restrict__ cmap,
                           const float* __restrict__ b0,
                           const float* __restrict__ b1,
                           const float* __restrict__ b2,
                           const ushort_t* __restrict__ W0p,
                           const ushort_t* __restrict__ W1p,
                           const ushort_t* __restrict__ W2p,
                           const int* __restrict__ tileTask,
                           const int* __restrict__ nTp,
                           const int* __restrict__ perm,
                           float* __restrict__ out) {
    __shared__ __align__(16) ushort_t H1[16384];    // 4 tt * 8 kt * 64 * 8 = 32 KB
    __shared__ __align__(16) ushort_t XH2[16384];   // X: frags [0,16) (16 KB); H2: frags [0,32)

    int b = blockIdx.x;
    if (b >= nTp[0]) return;
    int t = threadIdx.x;
    int task = tileTask[b];
    int c0 = cmap[task], c1 = cmap[16 + task], c2 = cmap[32 + task];

    int w = t >> 6;                 // wave 0..7
    int lane = t & 63;
    int l15 = lane & 15, lq = lane >> 4;

    // ---- stage X: gather + cvt straight into B-fragment order (two b128/thread)
    {
        int r = t >> 3, q = t & 7;             // token r, covers k = q*16..q*16+15
        int tok = perm[b * TILE + r];
        float4 v0 = make_float4(0.f, 0.f, 0.f, 0.f), v1 = v0, v2 = v0, v3 = v0;
        if ((unsigned)tok < (unsigned)N_TOK) {
            const float4* src = reinterpret_cast<const float4*>(x_in) + (size_t)tok * 32 + q * 4;
            v0 = src[0]; v1 = src[1]; v2 = src[2]; v3 = src[3];
        }
        // frag coords: kt = q>>1, fragid = (r>>4)*4 + kt
        // half h (m = h*8..h*8+7): lane' = (r&15) + 16*((q&1)*2 + h)
        int fragid = (r >> 4) * 4 + (q >> 1);
        int lp0 = (r & 15) + 16 * ((q & 1) * 2);
        uint4 pk0, pk1;
        pk0.x = pk2(v0.x, v0.y); pk0.y = pk2(v0.z, v0.w);
        pk0.z = pk2(v1.x, v1.y); pk0.w = pk2(v1.z, v1.w);
        pk1.x = pk2(v2.x, v2.y); pk1.y = pk2(v2.z, v2.w);
        pk1.z = pk2(v3.x, v3.y); pk1.w = pk2(v3.z, v3.w);
        *reinterpret_cast<uint4*>(&XH2[(fragid * 64 + lp0) << 3]) = pk0;
        *reinterpret_cast<uint4*>(&XH2[(fragid * 64 + lp0 + 16) << 3]) = pk1;
    }
    __syncthreads();

    // ---- Layer 0: H1^T = W0^T X^T. Wave w: feature tiles {2w,2w+1} x 4 token tiles.
    {
        f4v acc[2][4];
#pragma unroll
        for (int mi = 0; mi < 2; mi++) {
            float4 bv = *reinterpret_cast<const float4*>(b0 + c0 * 256 + (2 * w + mi) * 16 + lq * 4);
#pragma unroll
            for (int nt = 0; nt < 4; nt++) {
                acc[mi][nt][0] = bv.x; acc[mi][nt][1] = bv.y;
                acc[mi][nt][2] = bv.z; acc[mi][nt][3] = bv.w;
            }
        }
        const ushort_t* Wc = W0p + (size_t)c0 * 32768;
#pragma unroll
        for (int kt = 0; kt < 4; kt++) {
            s8v wa[2];
#pragma unroll
            for (int mi = 0; mi < 2; mi++)
                wa[mi] = *reinterpret_cast<const s8v*>(Wc + ((((2 * w + mi) * 4 + kt) * 64 + lane) << 3));
            s8v xb[4];
#pragma unroll
            for (int nt = 0; nt < 4; nt++)
                xb[nt] = *reinterpret_cast<const s8v*>(&XH2[((nt * 4 + kt) * 64 + lane) << 3]);
#pragma unroll
            for (int mi = 0; mi < 2; mi++)
#pragma unroll
                for (int nt = 0; nt < 4; nt++)
                    acc[mi][nt] = __builtin_amdgcn_mfma_f32_16x16x32_bf16(wa[mi], xb[nt], acc[mi][nt], 0, 0, 0);
        }
#pragma unroll
        for (int mi = 0; mi < 2; mi++) {
            int ft = 2 * w + mi;
            int kt_h = ft >> 1;
            int lanep = l15 + 16 * ((ft & 1) * 2 + (lq >> 1));
            int j0 = (lq & 1) * 4;
#pragma unroll
            for (int nt = 0; nt < 4; nt++) {
                float t0 = tanh_fast(acc[mi][nt][0]);
                float t1 = tanh_fast(acc[mi][nt][1]);
                float t2 = tanh_fast(acc[mi][nt][2]);
                float t3 = tanh_fast(acc[mi][nt][3]);
                uint2 pk; pk.x = pk2(t0, t1); pk.y = pk2(t2, t3);
                *reinterpret_cast<uint2*>(&H1[(((nt * 8 + kt_h) * 64 + lanep) << 3) + j0]) = pk;
            }
        }
    }
    __syncthreads();

    // ---- Layer 1: H2^T = W1^T H1^T. (H2 overlays X region.)
    {
        f4v acc[2][4];
#pragma unroll
        for (int mi = 0; mi < 2; mi++) {
            float4 bv = *reinterpret_cast<const float4*>(b1 + c1 * 256 + (2 * w + mi) * 16 + lq * 4);
#pragma unroll
            for (int nt = 0; nt < 4; nt++) {
                acc[mi][nt][0] = bv.x; acc[mi][nt][1] = bv.y;
                acc[mi][nt][2] = bv.z; acc[mi][nt][3] = bv.w;
            }
        }
        const ushort_t* Wc = W1p + (size_t)c1 * 65536;
#pragma unroll
        for (int kt = 0; kt < 8; kt++) {
            s8v wa[2];
#pragma unroll
            for (int mi = 0; mi < 2; mi++)
                wa[mi] = *reinterpret_cast<const s8v*>(Wc + ((((2 * w + mi) * 8 + kt) * 64 + lane) << 3));
            s8v xb[4];
#pragma unroll
            for (int nt = 0; nt < 4; nt++)
                xb[nt] = *reinterpret_cast<const s8v*>(&H1[((nt * 8 + kt) * 64 + lane) << 3]);
#pragma unroll
            for (int mi = 0; mi < 2; mi++)
#pragma unroll
                for (int nt = 0; nt < 4; nt++)
                    acc[mi][nt] = __builtin_amdgcn_mfma_f32_16x16x32_bf16(wa[mi], xb[nt], acc[mi][nt], 0, 0, 0);
        }
#pragma unroll
        for (int mi = 0; mi < 2; mi++) {
            int ft = 2 * w + mi;
            int kt_h = ft >> 1;
            int lanep = l15 + 16 * ((ft & 1) * 2 + (lq >> 1));
            int j0 = (lq & 1) * 4;
#pragma unroll
            for (int nt = 0; nt < 4; nt++) {
                float t0 = tanh_fast(acc[mi][nt][0]);
                float t1 = tanh_fast(acc[mi][nt][1]);
                float t2 = tanh_fast(acc[mi][nt][2]);
                float t3 = tanh_fast(acc[mi][nt][3]);
                uint2 pk; pk.x = pk2(t0, t1); pk.y = pk2(t2, t3);
                *reinterpret_cast<uint2*>(&XH2[(((nt * 8 + kt_h) * 64 + lanep) << 3) + j0]) = pk;
            }
        }
    }
    __syncthreads();

    // ---- Layer 2: O^T = W2^T H2^T. 4 mt x 4 nt tiles / 8 waves = 2 tiles/wave.
    {
        int mt = w & 3, ntb = (w >> 2) * 2;
        float4 bv = *reinterpret_cast<const float4*>(b2 + c2 * 64 + mt * 16 + lq * 4);
        f4v acc[2];
#pragma unroll
        for (int e = 0; e < 2; e++) {
            acc[e][0] = bv.x; acc[e][1] = bv.y; acc[e][2] = bv.z; acc[e][3] = bv.w;
        }
        const ushort_t* Wc = W2p + (size_t)c2 * 16384;
#pragma unroll
        for (int kt = 0; kt < 8; kt++) {
            s8v wa = *reinterpret_cast<const s8v*>(Wc + (((mt * 8 + kt) * 64 + lane) << 3));
#pragma unroll
            for (int e = 0; e < 2; e++) {
                s8v xb = *reinterpret_cast<const s8v*>(&XH2[(((ntb + e) * 8 + kt) * 64 + lane) << 3]);
                acc[e] = __builtin_amdgcn_mfma_f32_16x16x32_bf16(wa, xb, acc[e], 0, 0, 0);
            }
        }
#pragma unroll
        for (int e = 0; e < 2; e++) {
            int nt = ntb + e;
            int tok = perm[b * TILE + nt * 16 + l15];
            if ((unsigned)tok < (unsigned)N_TOK) {
                float4 o;
                o.x = acc[e][0]; o.y = acc[e][1]; o.z = acc[e][2]; o.w = acc[e][3];
                *reinterpret_cast<float4*>(out + (size_t)tok * 64 + mt * 16 + lq * 4) = o;
            }
        }
    }
}

// ---------------------------------------------------------------- launch
extern "C" void kernel_launch(void* const* d_in, const int* in_sizes, int n_in,
                              void* d_out, int out_size, void* d_ws, size_t ws_size,
                              hipStream_t stream) {
    const float* inputs = (const float*)d_in[0];
    const int*   task   = (const int*)d_in[1];
    const int*   cmap   = (const int*)d_in[2];
    const float* W0     = (const float*)d_in[3];
    const float* b0     = (const float*)d_in[4];
    const float* W1     = (const float*)d_in[5];
    const float* b1     = (const float*)d_in[6];
    const float* W2     = (const float*)d_in[7];
    const float* b2     = (const float*)d_in[8];
    float* out = (float*)d_out;

    char* ws = (char*)d_ws;
    int* blockCounts = (int*)(ws + 0);            // 64*16*4 = 4096 B
    int* nT          = (int*)(ws + 4096);         // 4 B (pad to 64)
    int* tileTask    = (int*)(ws + 4160);         // 2064*4 = 8256 B
    int* perm        = (int*)(ws + 12416);        // 2064*64*4 = 528384 B
    ushort_t* W0p    = (ushort_t*)(ws + 540800);  // 262144 B
    ushort_t* W1p    = (ushort_t*)(ws + 802944);  // 524288 B
    ushort_t* W2p    = (ushort_t*)(ws + 1327232); // 131072 B -> total ~1.39 MB

    prep_hist_kernel<<<288, 256, 0, stream>>>(W0, W1, W2, W0p, W1p, W2p, task, blockCounts);
    sort_kernel<<<64, 256, 0, stream>>>(task, blockCounts, tileTask, nT, perm);
    mlp_kernel<<<NT_MAX, 512, 0, stream>>>(inputs, cmap, b0, b1, b2,
                                           W0p, W1p, W2p, tileTask, nT, perm, out);
}

// Round 3
// 160.514 us; speedup vs baseline: 1.0422x; 1.0104x over previous
//
#include <hip/hip_runtime.h>

#define N_TOK 131072
#define TILE 64              // tokens per tile
#define NT_MAX 2064          // N_TOK/TILE + 16 tasks worth of padding tiles
#define NBLK 256             // 16 tasks x 16 blocks, 1 block/CU, weights in registers

typedef __attribute__((ext_vector_type(8))) short s8v;
typedef __attribute__((ext_vector_type(4))) float f4v;
typedef unsigned short ushort_t;

__device__ __forceinline__ unsigned short f2bf(float x) {
    union { float f; unsigned u; } v; v.f = x;
    unsigned r = v.u + 0x7fffu + ((v.u >> 16) & 1u);   // RNE (prep only)
    return (unsigned short)(r >> 16);
}

// round-half-up pack of two f32 -> packed bf16x2 via v_perm_b32 (3 VALU ops)
__device__ __forceinline__ unsigned pk2(float a, float b) {
    union { float f; unsigned u; } x, y; x.f = a; y.f = b;
    return __byte_perm(x.u + 0x8000u, y.u + 0x8000u, 0x7632);
}

// tanh via fast exp + fast rcp: mul, exp, add, rcp, fma (no precise-div sequence)
__device__ __forceinline__ float tanh_fast(float x) {
    float e = __expf(2.0f * x);
    float r = __builtin_amdgcn_rcpf(e + 1.0f);
    return __builtin_fmaf(-2.0f, r, 1.0f);
}

// ------------------------------------------------- fused prep + hist
// blocks [0,224): repack weights to bf16 MFMA fragments (one 16B write/thread).
// Fragment r = (ftile*(K>>5)+kt)*64 + lane; elem j holds W[k][n] with
// n = ftile*16 + (lane&15), k = kt*32 + (lane>>4)*8 + j.  (A operand of
// Y^T = W^T X^T.)   blocks [224,288): 16-bin histogram of task[].
__global__ void prep_hist_kernel(const float* __restrict__ W0, const float* __restrict__ W1,
                                 const float* __restrict__ W2,
                                 ushort_t* __restrict__ W0p, ushort_t* __restrict__ W1p,
                                 ushort_t* __restrict__ W2p,
                                 const int* __restrict__ task, int* __restrict__ blockCounts) {
    if (blockIdx.x < 224) {
        int f = blockIdx.x * 256 + threadIdx.x;   // 57344 total fragments
        const float* src; ushort_t* dst; int K, N;
        if (f < 16384)      { src = W0; dst = W0p; K = 128; N = 256; }
        else if (f < 49152) { src = W1; dst = W1p; K = 256; N = 256; f -= 16384; }
        else                { src = W2; dst = W2p; K = 256; N = 64;  f -= 49152; }
        int fpc = (N >> 4) * (K >> 5) * 64;       // fragments per copy
        int c = f / fpc, r = f % fpc;
        int lane = r & 63;
        int kt = (r >> 6) % (K >> 5);
        int ftile = (r >> 6) / (K >> 5);
        int n = ftile * 16 + (lane & 15);
        int kbase = kt * 32 + (lane >> 4) * 8;
        const float* s = src + (size_t)c * K * N + (size_t)kbase * N + n;
        s8v pk;
#pragma unroll
        for (int j = 0; j < 8; j++) pk[j] = (short)f2bf(s[(size_t)j * N]);
        *reinterpret_cast<s8v*>(dst + ((size_t)(c * fpc + r) << 3)) = pk;
    } else {
        __shared__ int cnt[16];
        int t = threadIdx.x;
        int hb = blockIdx.x - 224;
        if (t < 16) cnt[t] = 0;
        __syncthreads();
        int base = hb * 2048 + t;
#pragma unroll
        for (int i = 0; i < 8; i++) atomicAdd(&cnt[task[base + i * 256]], 1);
        __syncthreads();
        if (t < 16) blockCounts[hb * 16 + t] = cnt[t];
    }
}

// ------------------------------------------------- fused scan + scatter
// Exports tbase[17] (tile range per task) for the persistent mlp kernel.
__global__ void sort_kernel(const int* __restrict__ task, const int* __restrict__ blockCounts,
                            int* __restrict__ tbaseG, int* __restrict__ perm) {
    __shared__ int cntLds[1024];
    __shared__ int total[16], pref[16], rank[16];
    __shared__ int tokBase[16], tbase[17];
    int t = threadIdx.x, b = blockIdx.x;
    for (int i = t; i < 1024; i += 256) cntLds[i] = blockCounts[i];
    if (t < 16) rank[t] = 0;
    __syncthreads();
    if (t < 16) {
        int tot = 0, pf = 0;
#pragma unroll
        for (int bb = 0; bb < 64; bb++) {
            int v = cntLds[bb * 16 + t];
            tot += v;
            if (bb < b) pf += v;
        }
        total[t] = tot; pref[t] = pf;
    }
    __syncthreads();
    if (t == 0) {
        int tok = 0, tile = 0;
        for (int k = 0; k < 16; k++) {
            tokBase[k] = tok;
            tbase[k] = tile;
            int ntk = (total[k] + TILE - 1) / TILE;
            tok += ntk * TILE;
            tile += ntk;
        }
        tbase[16] = tile;
    }
    __syncthreads();
    if (b == 0) {
        if (t < 17) tbaseG[t] = tbase[t];
        // fill padding slots with -1 (don't rely on ws poison being >= N_TOK)
        for (int i = t; i < 16 * TILE; i += 256) {
            int k = i >> 6, off = i & (TILE - 1);
            int idx = total[k] + off;
            int lim = ((total[k] + TILE - 1) / TILE) * TILE;
            if (idx < lim) perm[tokBase[k] + idx] = -1;
        }
    }
    int tk[8], my[8];
#pragma unroll
    for (int i = 0; i < 8; i++) {
        int idx = b * 2048 + i * 256 + t;
        tk[i] = task[idx];
        my[i] = atomicAdd(&rank[tk[i]], 1);
    }
#pragma unroll
    for (int i = 0; i < 8; i++) {
        int idx = b * 2048 + i * 256 + t;
        perm[tokBase[tk[i]] + pref[tk[i]] + my[i]] = idx;
    }
}

// ------------------------------------------------- persistent weights-in-registers MLP
// Block p serves task p>>4 only: c0,c1,c2 fixed -> ALL weight fragments live in
// VGPRs (wa0 8 + wa1 16 + wa2 8 frags x 16B = 128 VGPR/lane), loaded ONCE per
// block. Inner loop over tiles (stride 16 within the task's tile range) touches
// only LDS activations + register weights + MFMA + tanh. Next tile's X gather
// is prefetched into registers during compute (T14). 8 waves, 2 waves/SIMD.
__launch_bounds__(512, 2)
__global__ void mlp_kernel(const float* __restrict__ x_in,
                           const int* __restrict__ cmap,
                           const float* __restrict__ b0,
                           const float* __restrict__ b1,
                           const float* __restrict__ b2,
                           const ushort_t* __restrict__ W0p,
                           const ushort_t* __restrict__ W1p,
                           const ushort_t* __restrict__ W2p,
                           const int* __restrict__ tbaseG,
                           const int* __restrict__ perm,
                           float* __restrict__ out) {
    __shared__ __align__(16) ushort_t H1[16384];    // 4 tt * 8 kt * 64 * 8 = 32 KB
    __shared__ __align__(16) ushort_t XH2[16384];   // X: frags [0,16); H2: frags [0,32)

    int p = blockIdx.x;
    int k = p >> 4, sub = p & 15;
    int tBeg = tbaseG[k], tEnd = tbaseG[k + 1];
    if (tBeg + sub >= tEnd) return;

    int t = threadIdx.x;
    int c0 = cmap[k], c1 = cmap[16 + k], c2 = cmap[32 + k];

    int w = t >> 6;                 // wave 0..7
    int lane = t & 63;
    int l15 = lane & 15, lq = lane >> 4;
    int mt2 = w & 3, ntb2 = (w >> 2) * 2;   // layer-2 tile assignment

    // ---- load ALL weight fragments for this task's copies into registers
    s8v wa0[2][4], wa1[2][8], wa2r[8];
    {
        const ushort_t* Wc = W0p + (size_t)c0 * 32768;
#pragma unroll
        for (int mi = 0; mi < 2; mi++)
#pragma unroll
            for (int kt = 0; kt < 4; kt++)
                wa0[mi][kt] = *reinterpret_cast<const s8v*>(Wc + ((((2 * w + mi) * 4 + kt) * 64 + lane) << 3));
    }
    {
        const ushort_t* Wc = W1p + (size_t)c1 * 65536;
#pragma unroll
        for (int mi = 0; mi < 2; mi++)
#pragma unroll
            for (int kt = 0; kt < 8; kt++)
                wa1[mi][kt] = *reinterpret_cast<const s8v*>(Wc + ((((2 * w + mi) * 8 + kt) * 64 + lane) << 3));
    }
    {
        const ushort_t* Wc = W2p + (size_t)c2 * 16384;
#pragma unroll
        for (int kt = 0; kt < 8; kt++)
            wa2r[kt] = *reinterpret_cast<const s8v*>(Wc + (((mt2 * 8 + kt) * 64 + lane) << 3));
    }
    // biases, resident
    float4 bv0[2], bv1[2], bv2;
#pragma unroll
    for (int mi = 0; mi < 2; mi++) {
        bv0[mi] = *reinterpret_cast<const float4*>(b0 + c0 * 256 + (2 * w + mi) * 16 + lq * 4);
        bv1[mi] = *reinterpret_cast<const float4*>(b1 + c1 * 256 + (2 * w + mi) * 16 + lq * 4);
    }
    bv2 = *reinterpret_cast<const float4*>(b2 + c2 * 64 + mt2 * 16 + lq * 4);

    // ---- X prefetch state (gather + cvt into B-fragment order, 2 b128/thread)
    int r = t >> 3, q = t & 7;             // token r, covers k = q*16..q*16+15
    const float4* xbase = reinterpret_cast<const float4*>(x_in);
    float4 v0 = make_float4(0.f, 0.f, 0.f, 0.f), v1 = v0, v2 = v0, v3 = v0;
    int ptok = -1;

    int tile = tBeg + sub;
    {
        ptok = perm[tile * TILE + r];
        if ((unsigned)ptok < (unsigned)N_TOK) {
            const float4* src = xbase + (size_t)ptok * 32 + q * 4;
            v0 = src[0]; v1 = src[1]; v2 = src[2]; v3 = src[3];
        }
    }

    for (; tile < tEnd; tile += 16) {
        // ---- stage prefetched X into LDS fragment order
        {
            int fragid = (r >> 4) * 4 + (q >> 1);
            int lp0 = (r & 15) + 16 * ((q & 1) * 2);
            uint4 pk0, pk1;
            pk0.x = pk2(v0.x, v0.y); pk0.y = pk2(v0.z, v0.w);
            pk0.z = pk2(v1.x, v1.y); pk0.w = pk2(v1.z, v1.w);
            pk1.x = pk2(v2.x, v2.y); pk1.y = pk2(v2.z, v2.w);
            pk1.z = pk2(v3.x, v3.y); pk1.w = pk2(v3.z, v3.w);
            *reinterpret_cast<uint4*>(&XH2[(fragid * 64 + lp0) << 3]) = pk0;
            *reinterpret_cast<uint4*>(&XH2[(fragid * 64 + lp0 + 16) << 3]) = pk1;
        }
        // ---- issue next tile's gather (latency hides under L0+L1+L2)
        int ntile = tile + 16;
        if (ntile < tEnd) {
            ptok = perm[ntile * TILE + r];
            float4 z = make_float4(0.f, 0.f, 0.f, 0.f);
            float4 a0 = z, a1 = z, a2 = z, a3 = z;
            if ((unsigned)ptok < (unsigned)N_TOK) {
                const float4* src = xbase + (size_t)ptok * 32 + q * 4;
                a0 = src[0]; a1 = src[1]; a2 = src[2]; a3 = src[3];
            }
            v0 = a0; v1 = a1; v2 = a2; v3 = a3;
        }
        __syncthreads();

        // ---- Layer 0: H1^T = W0^T X^T. Wave w: feature tiles {2w,2w+1} x 4 token tiles.
        {
            f4v acc[2][4];
#pragma unroll
            for (int mi = 0; mi < 2; mi++)
#pragma unroll
                for (int nt = 0; nt < 4; nt++) {
                    acc[mi][nt][0] = bv0[mi].x; acc[mi][nt][1] = bv0[mi].y;
                    acc[mi][nt][2] = bv0[mi].z; acc[mi][nt][3] = bv0[mi].w;
                }
#pragma unroll
            for (int kt = 0; kt < 4; kt++) {
                s8v xb[4];
#pragma unroll
                for (int nt = 0; nt < 4; nt++)
                    xb[nt] = *reinterpret_cast<const s8v*>(&XH2[((nt * 4 + kt) * 64 + lane) << 3]);
#pragma unroll
                for (int mi = 0; mi < 2; mi++)
#pragma unroll
                    for (int nt = 0; nt < 4; nt++)
                        acc[mi][nt] = __builtin_amdgcn_mfma_f32_16x16x32_bf16(wa0[mi][kt], xb[nt], acc[mi][nt], 0, 0, 0);
            }
#pragma unroll
            for (int mi = 0; mi < 2; mi++) {
                int ft = 2 * w + mi;
                int kt_h = ft >> 1;
                int lanep = l15 + 16 * ((ft & 1) * 2 + (lq >> 1));
                int j0 = (lq & 1) * 4;
#pragma unroll
                for (int nt = 0; nt < 4; nt++) {
                    float t0 = tanh_fast(acc[mi][nt][0]);
                    float t1 = tanh_fast(acc[mi][nt][1]);
                    float t2 = tanh_fast(acc[mi][nt][2]);
                    float t3 = tanh_fast(acc[mi][nt][3]);
                    uint2 pk; pk.x = pk2(t0, t1); pk.y = pk2(t2, t3);
                    *reinterpret_cast<uint2*>(&H1[(((nt * 8 + kt_h) * 64 + lanep) << 3) + j0]) = pk;
                }
            }
        }
        __syncthreads();

        // ---- Layer 1: H2^T = W1^T H1^T. (H2 overlays X region.)
        {
            f4v acc[2][4];
#pragma unroll
            for (int mi = 0; mi < 2; mi++)
#pragma unroll
                for (int nt = 0; nt < 4; nt++) {
                    acc[mi][nt][0] = bv1[mi].x; acc[mi][nt][1] = bv1[mi].y;
                    acc[mi][nt][2] = bv1[mi].z; acc[mi][nt][3] = bv1[mi].w;
                }
#pragma unroll
            for (int kt = 0; kt < 8; kt++) {
                s8v xb[4];
#pragma unroll
                for (int nt = 0; nt < 4; nt++)
                    xb[nt] = *reinterpret_cast<const s8v*>(&H1[((nt * 8 + kt) * 64 + lane) << 3]);
#pragma unroll
                for (int mi = 0; mi < 2; mi++)
#pragma unroll
                    for (int nt = 0; nt < 4; nt++)
                        acc[mi][nt] = __builtin_amdgcn_mfma_f32_16x16x32_bf16(wa1[mi][kt], xb[nt], acc[mi][nt], 0, 0, 0);
            }
#pragma unroll
            for (int mi = 0; mi < 2; mi++) {
                int ft = 2 * w + mi;
                int kt_h = ft >> 1;
                int lanep = l15 + 16 * ((ft & 1) * 2 + (lq >> 1));
                int j0 = (lq & 1) * 4;
#pragma unroll
                for (int nt = 0; nt < 4; nt++) {
                    float t0 = tanh_fast(acc[mi][nt][0]);
                    float t1 = tanh_fast(acc[mi][nt][1]);
                    float t2 = tanh_fast(acc[mi][nt][2]);
                    float t3 = tanh_fast(acc[mi][nt][3]);
                    uint2 pk; pk.x = pk2(t0, t1); pk.y = pk2(t2, t3);
                    *reinterpret_cast<uint2*>(&XH2[(((nt * 8 + kt_h) * 64 + lanep) << 3) + j0]) = pk;
                }
            }
        }
        __syncthreads();

        // ---- Layer 2: O^T = W2^T H2^T. 4 mt x 4 nt tiles / 8 waves = 2 tiles/wave.
        {
            int tok0 = perm[tile * TILE + ntb2 * 16 + l15];        // issued early,
            int tok1 = perm[tile * TILE + (ntb2 + 1) * 16 + l15];  // hides under MFMA
            f4v acc[2];
#pragma unroll
            for (int e = 0; e < 2; e++) {
                acc[e][0] = bv2.x; acc[e][1] = bv2.y; acc[e][2] = bv2.z; acc[e][3] = bv2.w;
            }
#pragma unroll
            for (int kt = 0; kt < 8; kt++) {
#pragma unroll
                for (int e = 0; e < 2; e++) {
                    s8v xb = *reinterpret_cast<const s8v*>(&XH2[(((ntb2 + e) * 8 + kt) * 64 + lane) << 3]);
                    acc[e] = __builtin_amdgcn_mfma_f32_16x16x32_bf16(wa2r[kt], xb, acc[e], 0, 0, 0);
                }
            }
#pragma unroll
            for (int e = 0; e < 2; e++) {
                int tok = e ? tok1 : tok0;
                if ((unsigned)tok < (unsigned)N_TOK) {
                    float4 o;
                    o.x = acc[e][0]; o.y = acc[e][1]; o.z = acc[e][2]; o.w = acc[e][3];
                    *reinterpret_cast<float4*>(out + (size_t)tok * 64 + mt2 * 16 + lq * 4) = o;
                }
            }
        }
        __syncthreads();   // XH2 (H2) reads done -> free for next tile's X
    }
}

// ---------------------------------------------------------------- launch
extern "C" void kernel_launch(void* const* d_in, const int* in_sizes, int n_in,
                              void* d_out, int out_size, void* d_ws, size_t ws_size,
                              hipStream_t stream) {
    const float* inputs = (const float*)d_in[0];
    const int*   task   = (const int*)d_in[1];
    const int*   cmap   = (const int*)d_in[2];
    const float* W0     = (const float*)d_in[3];
    const float* b0     = (const float*)d_in[4];
    const float* W1     = (const float*)d_in[5];
    const float* b1     = (const float*)d_in[6];
    const float* W2     = (const float*)d_in[7];
    const float* b2     = (const float*)d_in[8];
    float* out = (float*)d_out;

    char* ws = (char*)d_ws;
    int* blockCounts = (int*)(ws + 0);            // 64*16*4 = 4096 B
    int* tbaseG      = (int*)(ws + 4096);         // 17*4 = 68 B, padded to 128
    int* perm        = (int*)(ws + 4224);         // 2064*64*4 = 528384 B (was 4160: overlapped tbaseG[16]!)
    ushort_t* W0p    = (ushort_t*)(ws + 532608);  // 262144 B
    ushort_t* W1p    = (ushort_t*)(ws + 794752);  // 524288 B
    ushort_t* W2p    = (ushort_t*)(ws + 1319040); // 131072 B -> total ~1.38 MB

    prep_hist_kernel<<<288, 256, 0, stream>>>(W0, W1, W2, W0p, W1p, W2p, task, blockCounts);
    sort_kernel<<<64, 256, 0, stream>>>(task, blockCounts, tbaseG, perm);
    mlp_kernel<<<NBLK, 512, 0, stream>>>(inputs, cmap, b0, b1, b2,
                                         W0p, W1p, W2p, tbaseG, perm, out);
}